// Round 1
// baseline (58.099 us; speedup 1.0000x reference)
//
#include <hip/hip_runtime.h>
#include <hip/hip_bf16.h>

// Problem constants (from setup_inputs): features [16, 512, 56, 56] f32, k=3 -> d=1
#define BB 16
#define CC 512
#define HH 56
#define WW 56
#define HW (HH * WW)

__device__ __forceinline__ float shfl64(float v, int lane) {
    return __shfl(v, lane, 64);
}

// Each wave handles one output row y (lane = x). Loop over CCHUNK channels,
// accumulating the six per-pixel channel sums:
//   s12h = sum f1*f2, s11 = sum f1^2, s22 = sum f2^2   (horizontal pair)
//   s12v = sum f3*f4, s33 = sum f3^2, s44 = sum f4^2   (vertical pair)
// where (1/9 scale and masks cancel in the cosine ratio and are dropped):
//   V  = mym*g(y-1) + g(y) + myp*g(y+1)              (vertical zero-padded 3-sum)
//   f1 = mxm*V(cl(x-2)) + V(cl(x-1)) + mxp*V(x)      (shift-right then conv)
//   f2 = mxm*V(x) + V(cl(x+1)) + mxp*V(cl(x+2))      (shift-left  then conv)
//   w3 = mym*g(y) + g(cl(y+1)) + myp*g(cl(y+2))      (shift-top rows, conv vert part)
//   w4 = mym*g(cl(y-2)) + g(cl(y-1)) + myp*g(y)      (shift-bot rows)
//   f3 = mxm*w3(x-1) + w3(x) + mxp*w3(x+1)
//   f4 = mxm*w4(x-1) + w4(x) + mxp*w4(x+1)
template <int CCHUNK, bool WRITE_OUT>
__global__ __launch_bounds__(256) void ComputeTotalSim_84267258347855_kernel(
    const float* __restrict__ feat, float* __restrict__ acc, float* __restrict__ out) {
    const int b = blockIdx.z;
    const int ystrip = blockIdx.y;
    const int wave = threadIdx.x >> 6;
    const int lane = threadIdx.x & 63;
    const int x = lane;
    const int y = ystrip * 4 + wave;

    const int xc = x < WW ? x : (WW - 1);          // clamp for load safety (lanes 56..63)
    const float mxm = (x >= 1) ? 1.f : 0.f;
    const float mxp = (x <= WW - 2) ? 1.f : 0.f;
    const float mym = (y >= 1) ? 1.f : 0.f;
    const float myp = (y <= HH - 2) ? 1.f : 0.f;

    const int lm2 = x >= 2 ? x - 2 : 0;
    const int lm1 = x >= 1 ? x - 1 : 0;
    const int lp1 = (x + 1 <= WW - 1) ? x + 1 : WW - 1;
    const int lp2 = (x + 2 <= WW - 1) ? x + 2 : WW - 1;

    const int ry0 = (y - 2 < 0) ? 0 : y - 2;
    const int ry1 = (y - 1 < 0) ? 0 : y - 1;
    const int ry2 = y;
    const int ry3 = (y + 1 > HH - 1) ? HH - 1 : y + 1;
    const int ry4 = (y + 2 > HH - 1) ? HH - 1 : y + 2;

    const int o0 = ry0 * WW + xc, o1 = ry1 * WW + xc, o2 = ry2 * WW + xc,
              o3 = ry3 * WW + xc, o4 = ry4 * WW + xc;

    const float* p = feat + ((size_t)b * CC + (size_t)blockIdx.x * CCHUNK) * HW;

    float s12h = 0.f, s11 = 0.f, s22 = 0.f, s12v = 0.f, s33 = 0.f, s44 = 0.f;
#pragma unroll 4
    for (int c = 0; c < CCHUNK; ++c, p += HW) {
        const float r0 = p[o0], r1 = p[o1], r2 = p[o2], r3 = p[o3], r4 = p[o4];
        const float V  = fmaf(mym, r1, fmaf(myp, r3, r2));
        const float w3 = fmaf(mym, r2, fmaf(myp, r4, r3));
        const float w4 = fmaf(mym, r0, fmaf(myp, r2, r1));
        const float Vm2 = shfl64(V, lm2), Vm1 = shfl64(V, lm1);
        const float Vp1 = shfl64(V, lp1), Vp2 = shfl64(V, lp2);
        const float f1 = fmaf(mxm, Vm2, fmaf(mxp, V, Vm1));
        const float f2 = fmaf(mxm, V, fmaf(mxp, Vp2, Vp1));
        const float f3 = fmaf(mxm, shfl64(w3, lm1), fmaf(mxp, shfl64(w3, lp1), w3));
        const float f4 = fmaf(mxm, shfl64(w4, lm1), fmaf(mxp, shfl64(w4, lp1), w4));
        s12h = fmaf(f1, f2, s12h);
        s11  = fmaf(f1, f1, s11);
        s22  = fmaf(f2, f2, s22);
        s12v = fmaf(f3, f4, s12v);
        s33  = fmaf(f3, f3, s33);
        s44  = fmaf(f4, f4, s44);
    }

    if (x < WW) {
        const size_t pix = (size_t)b * HW + (size_t)y * WW + x;
        if (WRITE_OUT) {
            const double num = 0.5 * ((double)s12h / sqrt((double)s11 * (double)s22) +
                                      (double)s12v / sqrt((double)s33 * (double)s44));
            out[pix] = (float)num;
        } else {
            const size_t N = (size_t)BB * HW;
            atomicAdd(&acc[0 * N + pix], s12h);
            atomicAdd(&acc[1 * N + pix], s11);
            atomicAdd(&acc[2 * N + pix], s22);
            atomicAdd(&acc[3 * N + pix], s12v);
            atomicAdd(&acc[4 * N + pix], s33);
            atomicAdd(&acc[5 * N + pix], s44);
        }
    }
}

__global__ void ComputeTotalSim_finalize(const float* __restrict__ acc,
                                         float* __restrict__ out) {
    const int i = blockIdx.x * blockDim.x + threadIdx.x;
    const int N = BB * HW;
    if (i < N) {
        const double s12h = acc[i],         s11 = acc[N + i],     s22 = acc[2 * N + i];
        const double s12v = acc[3 * N + i], s33 = acc[4 * N + i], s44 = acc[5 * N + i];
        out[i] = (float)(0.5 * (s12h / sqrt(s11 * s22) + s12v / sqrt(s33 * s44)));
    }
}

extern "C" void kernel_launch(void* const* d_in, const int* in_sizes, int n_in,
                              void* d_out, int out_size, void* d_ws, size_t ws_size,
                              hipStream_t stream) {
    const float* feat = (const float*)d_in[0];
    float* out = (float*)d_out;

    const size_t need = 6ull * BB * HW * sizeof(float);
    if (ws_size >= need) {
        // Two-phase: channel-chunked partial sums via atomics, then finalize.
        hipMemsetAsync(d_ws, 0, need, stream);
        dim3 grid(CC / 64, HH / 4, BB);  // 8 c-chunks x 14 y-strips x 16 batches
        ComputeTotalSim_84267258347855_kernel<64, false>
            <<<grid, 256, 0, stream>>>(feat, (float*)d_ws, out);
        ComputeTotalSim_finalize<<<(BB * HW + 255) / 256, 256, 0, stream>>>(
            (const float*)d_ws, out);
    } else {
        // Fallback: one block does all channels, writes output directly.
        dim3 grid(1, HH / 4, BB);
        ComputeTotalSim_84267258347855_kernel<CC, true>
            <<<grid, 256, 0, stream>>>(feat, nullptr, out);
    }
}